// Round 1
// baseline (290.846 us; speedup 1.0000x reference)
//
#include <hip/hip_runtime.h>
#include <hip/hip_bf16.h>
#include <stdint.h>

#define G_    128
#define NP_   1024
#define F_    16
#define K_    16
#define H_    64
#define L_    64
#define OUT_  128

// ---------------------------------------------------------------------------
// Kernel A: per-point u/v tables.
//   u[p][h] = b1[h] + sum_f x[p][f] * (W1[f][h] - W1[16+f][h])
//   v[p][h] =          sum_f x[p][f] *  W1[16+f][h]
// wave-per-point, lane = h (64 dims). W columns held in registers.
// ---------------------------------------------------------------------------
__global__ __launch_bounds__(256) void uv_kernel(
    const float* __restrict__ x, const float* __restrict__ W1,
    const float* __restrict__ b1, float* __restrict__ u, float* __restrict__ v)
{
    const int lane = threadIdx.x & 63;
    const int wave = threadIdx.x >> 6;

    float wb[16], wd[16];
#pragma unroll
    for (int f = 0; f < 16; ++f) {
        float wt  = W1[f * 64 + lane];
        float wbo = W1[(16 + f) * 64 + lane];
        wb[f] = wbo;
        wd[f] = wt - wbo;
    }
    const float bias = b1[lane];

    const int base = blockIdx.x * 64 + wave * 16;   // grid=2048 -> 131072 pts
    for (int n = 0; n < 16; ++n) {
        const int p = base + n;
        const float4* xr = (const float4*)(x + (size_t)p * 16);
        float4 a0 = xr[0], a1 = xr[1], a2 = xr[2], a3 = xr[3];  // broadcast L1
        float xv[16] = {a0.x,a0.y,a0.z,a0.w, a1.x,a1.y,a1.z,a1.w,
                        a2.x,a2.y,a2.z,a2.w, a3.x,a3.y,a3.z,a3.w};
        float uu = bias, vv = 0.f;
#pragma unroll
        for (int f = 0; f < 16; ++f) {
            uu = fmaf(xv[f], wd[f], uu);
            vv = fmaf(xv[f], wb[f], vv);
        }
        u[(size_t)p * 64 + lane] = uu;   // 256B coalesced per wave
        v[(size_t)p * 64 + lane] = vv;
    }
}

// ---------------------------------------------------------------------------
// Kernel B: kNN (K=16 smallest of 1024 squared distances per point).
// Thread-per-point; group's x staged to LDS in two 512-point phases.
// Ranking key: d' = sq_j - 2*dot(x_i,x_j)  (sq_i dropped: constant per i).
// Top-16 kept as sorted 16-register list of packed floats
// (low 10 mantissa bits = j). Insert = 15x v_med3_f32 + 1 min, branch-guarded.
// ---------------------------------------------------------------------------
__global__ __launch_bounds__(256) void knn_kernel(
    const float* __restrict__ x, int* __restrict__ idxw)
{
    __shared__ float xs[512 * 16];   // 32 KB
    __shared__ float sqs[512];       //  2 KB
    const int g     = blockIdx.x >> 2;      // grid = G_*4 = 512
    const int chunk = blockIdx.x & 3;
    const float* xg = x + (size_t)g * NP_ * F_;
    const int i = chunk * 256 + threadIdx.x;

    float xi[16];
    {
        const float4* xir = (const float4*)(xg + i * 16);
        float4 c0 = xir[0], c1 = xir[1], c2 = xir[2], c3 = xir[3];
        xi[0]=c0.x; xi[1]=c0.y; xi[2]=c0.z; xi[3]=c0.w;
        xi[4]=c1.x; xi[5]=c1.y; xi[6]=c1.z; xi[7]=c1.w;
        xi[8]=c2.x; xi[9]=c2.y; xi[10]=c2.z; xi[11]=c2.w;
        xi[12]=c3.x; xi[13]=c3.y; xi[14]=c3.z; xi[15]=c3.w;
    }

    float hp[16];                         // ascending; hp[15] = threshold
#pragma unroll
    for (int m = 0; m < 16; ++m) hp[m] = __uint_as_float(0x7F000000u); // big finite (NOT inf: index bits would make NaN)

    for (int ph = 0; ph < 2; ++ph) {
        __syncthreads();
        // stage 512 points (2048 float4, 8 per thread, coalesced)
        const float4* src = (const float4*)(xg + (size_t)ph * 512 * 16);
        float4* dst = (float4*)xs;
        for (int t = threadIdx.x; t < 2048; t += 256) dst[t] = src[t];
        __syncthreads();
        for (int p = threadIdx.x; p < 512; p += 256) {
            float s = 0.f;
#pragma unroll
            for (int f = 0; f < 16; ++f) { float w = xs[p * 16 + f]; s = fmaf(w, w, s); }
            sqs[p] = s;
        }
        __syncthreads();

        const int jbase = ph * 512;
        for (int jj = 0; jj < 512; ++jj) {
            float d0 = 0.f, d1 = 0.f, d2 = 0.f, d3 = 0.f;   // 4-way ILP
#pragma unroll
            for (int f = 0; f < 16; f += 4) {
                d0 = fmaf(xi[f+0], xs[jj*16+f+0], d0);
                d1 = fmaf(xi[f+1], xs[jj*16+f+1], d1);
                d2 = fmaf(xi[f+2], xs[jj*16+f+2], d2);
                d3 = fmaf(xi[f+3], xs[jj*16+f+3], d3);
            }
            float d = fmaf(-2.f, (d0 + d1) + (d2 + d3), sqs[jj]);
            if (d < hp[15]) {   // rare after warm-up -> execz-skipped body
                float dpf = __uint_as_float(
                    (__float_as_uint(d) & 0xFFFFFC00u) | (uint32_t)(jbase + jj));
#pragma unroll
                for (int m = 15; m >= 1; --m)
                    hp[m] = __builtin_amdgcn_fmed3f(dpf, hp[m-1], hp[m]);
                hp[0] = fminf(hp[0], dpf);
            }
        }
    }

    int* row = idxw + ((size_t)(g * NP_) + i) * K_;
#pragma unroll
    for (int m = 0; m < 16; ++m)
        row[m] = (int)(__float_as_uint(hp[m]) & 1023u);   // local j
}

// ---------------------------------------------------------------------------
// Kernel C: S[g][h] = sum_{i in g, k} relu(u_i[h] + v_{idx[i][k]}[h])
// wave-per-point-range, lane = h. v-rows are 256B wave-coalesced gathers
// from the group's 256KB L2-resident slice. One atomicAdd per lane per wave.
// ---------------------------------------------------------------------------
__global__ __launch_bounds__(256) void gather_kernel(
    const float* __restrict__ u, const float* __restrict__ v,
    const int* __restrict__ idxw, float* __restrict__ S)
{
    const int lane = threadIdx.x & 63;
    const int wave = threadIdx.x >> 6;
    const int pbase = blockIdx.x * 128 + wave * 32;   // grid = 1024
    const int g = pbase >> 10;
    const float* vg = v + (((size_t)g << 10) << 6);
    float acc = 0.f;
    for (int n = 0; n < 32; ++n) {
        const int ii = pbase + n;
        const float uu = u[(size_t)ii * 64 + lane];
        const int4* irow = (const int4*)(idxw + (size_t)ii * 16);
#pragma unroll
        for (int q = 0; q < 4; ++q) {
            int4 j4 = irow[q];   // broadcast
            float v0 = vg[(size_t)j4.x * 64 + lane];
            float v1 = vg[(size_t)j4.y * 64 + lane];
            float v2 = vg[(size_t)j4.z * 64 + lane];
            float v3 = vg[(size_t)j4.w * 64 + lane];
            acc += fmaxf(0.f, uu + v0);
            acc += fmaxf(0.f, uu + v1);
            acc += fmaxf(0.f, uu + v2);
            acc += fmaxf(0.f, uu + v3);
        }
    }
    atomicAdd(&S[(g << 6) + lane], acc);
}

// ---------------------------------------------------------------------------
// Kernel D: per-group head.  out[g] = ((S[g]/(NP*K)) @ W2 + b2) @ Wf + bf
// ---------------------------------------------------------------------------
__global__ __launch_bounds__(128) void head_kernel(
    const float* __restrict__ S, const float* __restrict__ W2,
    const float* __restrict__ b2, const float* __restrict__ Wf,
    const float* __restrict__ bf, float* __restrict__ out)
{
    __shared__ float hbar[64];
    __shared__ float t[64];
    const int g = blockIdx.x;
    const int tid = threadIdx.x;
    if (tid < 64) hbar[tid] = S[g * 64 + tid] * (1.f / (1024.f * 16.f));
    __syncthreads();
    if (tid < 64) {
        float a = b2[tid];
        for (int h = 0; h < 64; ++h) a = fmaf(hbar[h], W2[h * 64 + tid], a);
        t[tid] = a;
    }
    __syncthreads();
    float a = bf[tid];
    for (int h = 0; h < 64; ++h) a = fmaf(t[h], Wf[h * 128 + tid], a);
    out[g * 128 + tid] = a;
}

// ---------------------------------------------------------------------------
extern "C" void kernel_launch(void* const* d_in, const int* in_sizes, int n_in,
                              void* d_out, int out_size, void* d_ws, size_t ws_size,
                              hipStream_t stream)
{
    const float* x  = (const float*)d_in[0];
    // d_in[1] = batch (implied by contiguous 1024-point groups; unused)
    const float* W1 = (const float*)d_in[2];
    const float* b1 = (const float*)d_in[3];
    const float* W2 = (const float*)d_in[4];
    const float* b2 = (const float*)d_in[5];
    const float* Wf = (const float*)d_in[6];
    const float* bf = (const float*)d_in[7];
    float* out = (float*)d_out;

    char* ws = (char*)d_ws;
    const size_t N = (size_t)G_ * NP_;                 // 131072 points
    float* u    = (float*)ws;                          // N*64 f32 = 33.5 MB
    float* v    = (float*)(ws + N * 64 * 4);           // N*64 f32 = 33.5 MB
    int*   idxw = (int*)  (ws + 2 * N * 64 * 4);       // N*16 i32 =  8.4 MB
    float* S    = (float*)(ws + 2 * N * 64 * 4 + N * 16 * 4); // 32 KB

    hipMemsetAsync(S, 0, G_ * H_ * sizeof(float), stream);

    uv_kernel    <<<2048, 256, 0, stream>>>(x, W1, b1, u, v);
    knn_kernel   <<<G_ * 4, 256, 0, stream>>>(x, idxw);
    gather_kernel<<<1024, 256, 0, stream>>>(u, v, idxw, S);
    head_kernel  <<<G_, 128, 0, stream>>>(S, W2, b2, Wf, bf, out);
}

// Round 2
// 240.807 us; speedup vs baseline: 1.2078x; 1.2078x over previous
//
#include <hip/hip_runtime.h>
#include <hip/hip_bf16.h>
#include <stdint.h>

#define G_    128
#define NP_   1024
#define F_    16
#define K_    16
#define H_    64
#define L_    64
#define OUT_  128

#define SLAB   32
#define NSLAB  (NP_ / SLAB)
#define DSTRIDE 68   // floats; even (16B-aligned cols), (4j+q)%32 spreads banks

typedef short  short8v  __attribute__((ext_vector_type(8)));
typedef short  short4v  __attribute__((ext_vector_type(4)));
typedef float  float4v  __attribute__((ext_vector_type(4)));

__device__ __forceinline__ uint16_t bf_rne(float f) {
    uint32_t u = __float_as_uint(f);
    return (uint16_t)((u + 0x7FFFu + ((u >> 16) & 1u)) >> 16);
}
__device__ __forceinline__ float bf_to_f(uint16_t h) {
    return __uint_as_float((uint32_t)h << 16);
}

// ---------------------------------------------------------------------------
// Kernel A: per-point u/v tables (unchanged from R1).
// ---------------------------------------------------------------------------
__global__ __launch_bounds__(256) void uv_kernel(
    const float* __restrict__ x, const float* __restrict__ W1,
    const float* __restrict__ b1, float* __restrict__ u, float* __restrict__ v)
{
    const int lane = threadIdx.x & 63;
    const int wave = threadIdx.x >> 6;

    float wb[16], wd[16];
#pragma unroll
    for (int f = 0; f < 16; ++f) {
        float wt  = W1[f * 64 + lane];
        float wbo = W1[(16 + f) * 64 + lane];
        wb[f] = wbo;
        wd[f] = wt - wbo;
    }
    const float bias = b1[lane];

    const int base = blockIdx.x * 64 + wave * 16;
    for (int n = 0; n < 16; ++n) {
        const int p = base + n;
        const float4* xr = (const float4*)(x + (size_t)p * 16);
        float4 a0 = xr[0], a1 = xr[1], a2 = xr[2], a3 = xr[3];
        float xv[16] = {a0.x,a0.y,a0.z,a0.w, a1.x,a1.y,a1.z,a1.w,
                        a2.x,a2.y,a2.z,a2.w, a3.x,a3.y,a3.z,a3.w};
        float uu = bias, vv = 0.f;
#pragma unroll
        for (int f = 0; f < 16; ++f) {
            uu = fmaf(xv[f], wd[f], uu);
            vv = fmaf(xv[f], wb[f], vv);
        }
        u[(size_t)p * 64 + lane] = uu;
        v[(size_t)p * 64 + lane] = vv;
    }
}

// ---------------------------------------------------------------------------
// Kernel B: kNN via MFMA distance tiles.
// Block = 256 threads = 4 waves; block covers 256 queries of one group.
// Per wave: 64 queries. Per slab of 32 j:
//   dot(i,j) via 2x mfma_f32_16x16x32_bf16 (hi/lo split packed in K):
//     A1=[xh_i|xl_i], B1=[xh_j|xh_j]  -> hh + lh
//     A2=[xh_i|0  ],  B2=[xl_j|xl_j]  -> hl
//   d' = sq_j - 2*dot folded at C-write into per-wave LDS DT[j][q] (q-major
//   contiguous float4 writes; scan reads conflict-free b32 column walks).
// Top-16 per query: sorted 16-reg list, index packed in low 10 mantissa bits,
// insert = 15x v_med3_f32 (wave-any branch).
// ---------------------------------------------------------------------------
__global__ __launch_bounds__(256) void knn_kernel(
    const float* __restrict__ x, int* __restrict__ idxw)
{
    __shared__ float    DT[4][SLAB * DSTRIDE];  // 34816 B (per-wave private)
    __shared__ uint16_t zh[SLAB * 24];          // bf16 hi, row stride 48B
    __shared__ uint16_t zl[SLAB * 24];          // bf16 lo
    __shared__ float    sqs[NP_];               // exact fp32 |x_j|^2

    const int g     = blockIdx.x >> 2;
    const int chunk = blockIdx.x & 3;
    const float* xg = x + (size_t)g * NP_ * F_;
    const int tid  = threadIdx.x;
    const int lane = tid & 63;
    const int wave = tid >> 6;

    // --- sq_j for the whole group (exact fp32) ---
    for (int r = tid; r < NP_; r += 256) {
        const float4* p = (const float4*)(xg + (size_t)r * 16);
        float4 a = p[0], b = p[1], c = p[2], d = p[3];
        float s = a.x*a.x + a.y*a.y + a.z*a.z + a.w*a.w;
        s += b.x*b.x + b.y*b.y + b.z*b.z + b.w*b.w;
        s += c.x*c.x + c.y*c.y + c.z*c.z + c.w*c.w;
        s += d.x*d.x + d.y*d.y + d.z*d.z + d.w*d.w;
        sqs[r] = s;
    }

    // --- A fragments: wave's 64 query rows, 4 row-tiles of 16 ---
    // lane layout (self-consistent A/B mirror): row = lane&15,
    // k-octet group = lane>>4: groups 0,1 -> xh octets 0,1; groups 2,3 -> xl.
    const int qbase = chunk * 256 + wave * 64;
    const int arow  = lane & 15;
    const int agrp  = lane >> 4;
    const int aoct  = agrp & 1;
    short8v a1[4], a2[4];
#pragma unroll
    for (int rt = 0; rt < 4; ++rt) {
        const float* src = xg + (size_t)(qbase + rt * 16 + arow) * 16 + aoct * 8;
        float4 f0 = ((const float4*)src)[0];
        float4 f1 = ((const float4*)src)[1];
        float fv[8] = {f0.x,f0.y,f0.z,f0.w, f1.x,f1.y,f1.z,f1.w};
        short8v h, l;
#pragma unroll
        for (int i = 0; i < 8; ++i) {
            uint16_t hb = bf_rne(fv[i]);
            h[i] = (short)hb;
            l[i] = (short)bf_rne(fv[i] - bf_to_f(hb));
        }
        short8v zz = {0,0,0,0,0,0,0,0};
        a1[rt] = (agrp < 2) ? h : l;
        a2[rt] = (agrp < 2) ? h : zz;
    }

    float hp[16];
#pragma unroll
    for (int m = 0; m < 16; ++m) hp[m] = __uint_as_float(0x7F000000u);

    float* dtw = DT[wave];
    const int bcol  = lane & 15;
    const int bgrp4 = (lane >> 4) & 1;

    for (int sl = 0; sl < NSLAB; ++sl) {
        __syncthreads();   // zh/zl reusable (all waves past last slab's frag reads)
        // --- stage slab j-rows as bf16 hi/lo (128 tasks: 32 rows x 4 quads) ---
        if (tid < SLAB * 4) {
            const int row = tid >> 2, q4 = tid & 3;
            const float4 f = *(const float4*)(xg + (size_t)(sl * SLAB + row) * 16 + q4 * 4);
            uint16_t h0 = bf_rne(f.x), h1 = bf_rne(f.y), h2 = bf_rne(f.z), h3 = bf_rne(f.w);
            short4v hv = {(short)h0, (short)h1, (short)h2, (short)h3};
            short4v lv = {(short)bf_rne(f.x - bf_to_f(h0)), (short)bf_rne(f.y - bf_to_f(h1)),
                          (short)bf_rne(f.z - bf_to_f(h2)), (short)bf_rne(f.w - bf_to_f(h3))};
            *(short4v*)&zh[row * 24 + q4 * 4] = hv;
            *(short4v*)&zl[row * 24 + q4 * 4] = lv;
        }
        __syncthreads();

        // --- MFMA distance tiles + fold + transpose-store to DT ---
#pragma unroll
        for (int ct = 0; ct < SLAB / 16; ++ct) {
            short8v b1 = *(const short8v*)&zh[(ct * 16 + bcol) * 24 + bgrp4 * 8];
            short8v b2 = *(const short8v*)&zl[(ct * 16 + bcol) * 24 + bgrp4 * 8];
            const float sqv = sqs[sl * SLAB + ct * 16 + bcol];
#pragma unroll
            for (int rt = 0; rt < 4; ++rt) {
                float4v acc = {0.f, 0.f, 0.f, 0.f};
                acc = __builtin_amdgcn_mfma_f32_16x16x32_bf16(a1[rt], b1, acc, 0, 0, 0);
                acc = __builtin_amdgcn_mfma_f32_16x16x32_bf16(a2[rt], b2, acc, 0, 0, 0);
                // C layout: col(j) = lane&15, row(q) = (lane>>4)*4 + reg
                float4 outv;
                outv.x = fmaf(-2.f, acc[0], sqv);
                outv.y = fmaf(-2.f, acc[1], sqv);
                outv.z = fmaf(-2.f, acc[2], sqv);
                outv.w = fmaf(-2.f, acc[3], sqv);
                *(float4*)&dtw[(ct * 16 + bcol) * DSTRIDE + rt * 16 + (lane >> 4) * 4] = outv;
            }
        }
        // own-wave DT writes -> own-wave reads: drain LDS, block reordering
        asm volatile("s_waitcnt lgkmcnt(0)" ::: "memory");
        __builtin_amdgcn_sched_barrier(0);

        // --- scan this slab: thread t owns query (qbase + lane) ---
        const float* dtr = dtw + lane;
        const int jg0 = sl * SLAB;
#pragma unroll 4
        for (int j = 0; j < SLAB; ++j) {
            float d = dtr[j * DSTRIDE];
            if (d < hp[15]) {
                float dpf = __uint_as_float(
                    (__float_as_uint(d) & 0xFFFFFC00u) | (uint32_t)(jg0 + j));
#pragma unroll
                for (int m = 15; m >= 1; --m)
                    hp[m] = __builtin_amdgcn_fmed3f(dpf, hp[m - 1], hp[m]);
                hp[0] = fminf(hp[0], dpf);
            }
        }
    }

    int* row = idxw + ((size_t)(g * NP_) + chunk * 256 + wave * 64 + lane) * K_;
#pragma unroll
    for (int m = 0; m < 16; ++m)
        row[m] = (int)(__float_as_uint(hp[m]) & 1023u);
}

// ---------------------------------------------------------------------------
// Kernel C: S[g][h] = sum_{i,k} relu(u_i[h] + v_{idx[i][k]}[h])  (unchanged)
// ---------------------------------------------------------------------------
__global__ __launch_bounds__(256) void gather_kernel(
    const float* __restrict__ u, const float* __restrict__ v,
    const int* __restrict__ idxw, float* __restrict__ S)
{
    const int lane = threadIdx.x & 63;
    const int wave = threadIdx.x >> 6;
    const int pbase = blockIdx.x * 128 + wave * 32;
    const int g = pbase >> 10;
    const float* vg = v + (((size_t)g << 10) << 6);
    float acc = 0.f;
    for (int n = 0; n < 32; ++n) {
        const int ii = pbase + n;
        const float uu = u[(size_t)ii * 64 + lane];
        const int4* irow = (const int4*)(idxw + (size_t)ii * 16);
#pragma unroll
        for (int q = 0; q < 4; ++q) {
            int4 j4 = irow[q];
            float v0 = vg[(size_t)j4.x * 64 + lane];
            float v1 = vg[(size_t)j4.y * 64 + lane];
            float v2 = vg[(size_t)j4.z * 64 + lane];
            float v3 = vg[(size_t)j4.w * 64 + lane];
            acc += fmaxf(0.f, uu + v0);
            acc += fmaxf(0.f, uu + v1);
            acc += fmaxf(0.f, uu + v2);
            acc += fmaxf(0.f, uu + v3);
        }
    }
    atomicAdd(&S[(g << 6) + lane], acc);
}

// ---------------------------------------------------------------------------
// Kernel D: per-group head (unchanged).
// ---------------------------------------------------------------------------
__global__ __launch_bounds__(128) void head_kernel(
    const float* __restrict__ S, const float* __restrict__ W2,
    const float* __restrict__ b2, const float* __restrict__ Wf,
    const float* __restrict__ bf, float* __restrict__ out)
{
    __shared__ float hbar[64];
    __shared__ float t[64];
    const int g = blockIdx.x;
    const int tid = threadIdx.x;
    if (tid < 64) hbar[tid] = S[g * 64 + tid] * (1.f / (1024.f * 16.f));
    __syncthreads();
    if (tid < 64) {
        float a = b2[tid];
        for (int h = 0; h < 64; ++h) a = fmaf(hbar[h], W2[h * 64 + tid], a);
        t[tid] = a;
    }
    __syncthreads();
    float a = bf[tid];
    for (int h = 0; h < 64; ++h) a = fmaf(t[h], Wf[h * 128 + tid], a);
    out[g * 128 + tid] = a;
}

// ---------------------------------------------------------------------------
extern "C" void kernel_launch(void* const* d_in, const int* in_sizes, int n_in,
                              void* d_out, int out_size, void* d_ws, size_t ws_size,
                              hipStream_t stream)
{
    const float* x  = (const float*)d_in[0];
    const float* W1 = (const float*)d_in[2];
    const float* b1 = (const float*)d_in[3];
    const float* W2 = (const float*)d_in[4];
    const float* b2 = (const float*)d_in[5];
    const float* Wf = (const float*)d_in[6];
    const float* bf = (const float*)d_in[7];
    float* out = (float*)d_out;

    char* ws = (char*)d_ws;
    const size_t N = (size_t)G_ * NP_;
    float* u    = (float*)ws;
    float* v    = (float*)(ws + N * 64 * 4);
    int*   idxw = (int*)  (ws + 2 * N * 64 * 4);
    float* S    = (float*)(ws + 2 * N * 64 * 4 + N * 16 * 4);

    hipMemsetAsync(S, 0, G_ * H_ * sizeof(float), stream);

    uv_kernel    <<<2048, 256, 0, stream>>>(x, W1, b1, u, v);
    knn_kernel   <<<G_ * 4, 256, 0, stream>>>(x, idxw);
    gather_kernel<<<1024, 256, 0, stream>>>(u, v, idxw, S);
    head_kernel  <<<G_, 128, 0, stream>>>(S, W2, b2, Wf, bf, out);
}